// Round 2
// baseline (4833.698 us; speedup 1.0000x reference)
//
#include <hip/hip_runtime.h>
#include <math.h>

#define NFFT   1024
#define NHALF  512
#define HOPSZ  256
#define NMELS  80
#define NFREQ  513
#define BATCH  8
#define TFRAMES 1024
#define PADW   512
#define LPAD   (NFFT + (TFRAMES - 1) * HOPSZ)   // 262912
#define LOUT   (LPAD - 2 * PADW)                // 261888
#define NITER  60
#define PI_D   3.14159265358979323846

// ---------------------------------------------------------------- init tables
// twiddle table: tw[j] = e^{-2*pi*i*j/N}  (FORWARD twiddle; conjugate for inverse)
__global__ void k_init_tables(float* __restrict__ twr, float* __restrict__ twi,
                              float* __restrict__ win) {
    int j = blockIdx.x * 256 + threadIdx.x;
    if (j < NHALF) {
        double th = -2.0 * PI_D * (double)j / (double)NFFT;
        twr[j] = (float)cos(th);
        twi[j] = (float)sin(th);
    }
    if (j < NFFT) {
        win[j] = (float)(0.5 - 0.5 * cos(2.0 * PI_D * (double)j / (double)NFFT));
    }
}

// envinv[i] = 1/sum_t win[i-256t]^2 (or 1 where env ~ 0)
__global__ void k_env(const float* __restrict__ win, float* __restrict__ envinv) {
    int i = blockIdx.x * 256 + threadIdx.x;
    if (i >= LPAD) return;
    int thi = i / HOPSZ; if (thi > TFRAMES - 1) thi = TFRAMES - 1;
    int d = i - (NFFT - 1);
    int tlo = (d > 0) ? (d + HOPSZ - 1) / HOPSZ : 0;
    float e = 0.f;
    for (int t = tlo; t <= thi; ++t) { float w = win[i - t * HOPSZ]; e += w * w; }
    envinv[i] = (e > 1e-11f) ? (1.0f / e) : 1.0f;
}

__global__ void k_expmel(const float* __restrict__ mel, float* __restrict__ em) {
    int i = blockIdx.x * 256 + threadIdx.x;
    if (i < BATCH * NMELS * TFRAMES) em[i] = expf(mel[i]);
}

// mag[b,t,k] = max(0, sum_m fb[k,m] * exp(mel[b,m,t]))  — layout (b*T+t)*513+k
__global__ void k_mag(const float* __restrict__ em, const float* __restrict__ fb,
                      float* __restrict__ mag) {
    __shared__ float sm[NMELS];
    int f = blockIdx.x; int b = f >> 10; int t = f & 1023;
    int tid = threadIdx.x;
    if (tid < NMELS) sm[tid] = em[(b * NMELS + tid) * TFRAMES + t];
    __syncthreads();
    for (int k = tid; k < NFREQ; k += 128) {
        float acc = 0.f;
        const float* row = fb + k * NMELS;
        #pragma unroll 8
        for (int m = 0; m < NMELS; ++m) acc += row[m] * sm[m];
        mag[(size_t)f * NFREQ + k] = fmaxf(acc, 0.f);
    }
}

// ------------------------------------------------- Stockham radix-2, 1024 pts
// Autosorting, ping-pong LDS buffers. 10 stages (even) => result back in x.
// Table is e^{-2pi i j/N}:  sgn = +1 -> FORWARD DFT, sgn = -1 -> INVERSE (unscaled).
// (verified by hand against N=4 DFT)
__device__ __forceinline__ void fft1024(float* xr, float* xi, float* yr, float* yi,
                                        const float* twr, const float* twi,
                                        int tid, float sgn) {
    float *ar = xr, *ai = xi, *br = yr, *bi = yi;
    #pragma unroll
    for (int stage = 0; stage < 10; ++stage) {
        int s = 1 << stage;
        __syncthreads();
        #pragma unroll
        for (int r = 0; r < 2; ++r) {
            int bb = tid + r * 256;                // butterfly index, [0,512)
            int hi = bb & ~(s - 1);                // = p*s = twiddle index
            int o1 = bb + hi;
            float x0r = ar[bb],       x0i = ai[bb];
            float x1r = ar[bb + 512], x1i = ai[bb + 512];
            float wr = twr[hi], wi = sgn * twi[hi];
            float sr = x0r - x1r, si = x0i - x1i;
            br[o1]     = x0r + x1r;
            bi[o1]     = x0i + x1i;
            br[o1 + s] = sr * wr - si * wi;
            bi[o1 + s] = sr * wi + si * wr;
        }
        float* t0 = ar; ar = br; br = t0;
        float* t1 = ai; ai = bi; bi = t1;
    }
}

// ------------------------------- initial frames: irfft(mag * e^{i2pi ang}) * win
__global__ __launch_bounds__(256) void k_init_frames(
        const float* __restrict__ mag, const float* __restrict__ ang,
        const float* __restrict__ gtwr, const float* __restrict__ gtwi,
        const float* __restrict__ win, float* __restrict__ frames) {
    __shared__ float Xr[NFFT], Xi[NFFT], Yr[NFFT], Yi[NFFT];
    __shared__ float twr[NHALF], twi[NHALF];
    int f = blockIdx.x; int b = f >> 10; int t = f & 1023;
    int tid = threadIdx.x;
    twr[tid] = gtwr[tid]; twr[tid + 256] = gtwr[tid + 256];
    twi[tid] = gtwi[tid]; twi[tid + 256] = gtwi[tid + 256];
    const float* mrow = mag + (size_t)f * NFREQ;
    #pragma unroll
    for (int r = 0; r < 2; ++r) {
        int k = tid + r * 256;                     // 0..511
        float m = mrow[k];
        float a = ang[((size_t)b * NFREQ + k) * TFRAMES + t] * 6.283185307179586477f;
        float sn, cs; sincosf(a, &sn, &cs);
        float re = m * cs, im = m * sn;
        Xr[k] = re; Xi[k] = im;
        if (k >= 1) { Xr[NFFT - k] = re; Xi[NFFT - k] = -im; }
    }
    if (tid == 0) {
        float m = mrow[512];
        float a = ang[((size_t)b * NFREQ + 512) * TFRAMES + t] * 6.283185307179586477f;
        float sn, cs; sincosf(a, &sn, &cs);
        Xr[512] = m * cs; Xi[512] = m * sn;        // imag contributes nothing to Re(ifft)
    }
    fft1024(Xr, Xi, Yr, Yi, twr, twi, tid, -1.f);  // INVERSE (unscaled)
    __syncthreads();
    float* fr = frames + (size_t)f * NFFT;
    #pragma unroll
    for (int r = 0; r < 4; ++r) {
        int j = tid + r * 256;
        fr[j] = Xr[j] * win[j] * (1.0f / NFFT);
    }
}

// ------------------- overlap-add: frames -> signal (len LOUT, env-normalized)
__global__ void k_ola(const float* __restrict__ frames, const float* __restrict__ envinv,
                      float* __restrict__ out) {
    int i = blockIdx.x * 256 + threadIdx.x;
    int b = blockIdx.y;
    if (i >= LOUT) return;
    int ii = i + PADW;
    int thi = ii >> 8; if (thi > TFRAMES - 1) thi = TFRAMES - 1;
    int d = ii - (NFFT - 1);
    int tlo = (d > 0) ? ((d + HOPSZ - 1) >> 8) : 0;
    float acc = 0.f;
    const float* fb_ = frames + (size_t)b * TFRAMES * NFFT;
    for (int t = tlo; t <= thi; ++t) acc += fb_[t * NFFT + (ii - t * HOPSZ)];
    out[(size_t)b * LOUT + i] = acc * envinv[ii];
}

// -------- one GL step per frame: gather(reflect)+win -> rfft -> mag*phase -> irfft*win
__global__ __launch_bounds__(256) void k_glstep(
        const float* __restrict__ sig, const float* __restrict__ mag,
        const float* __restrict__ gtwr, const float* __restrict__ gtwi,
        const float* __restrict__ win, float* __restrict__ frames) {
    __shared__ float Xr[NFFT], Xi[NFFT], Yr[NFFT], Yi[NFFT];
    __shared__ float twr[NHALF], twi[NHALF];
    int f = blockIdx.x; int b = f >> 10; int t = f & 1023;
    int tid = threadIdx.x;
    twr[tid] = gtwr[tid]; twr[tid + 256] = gtwr[tid + 256];
    twi[tid] = gtwi[tid]; twi[tid + 256] = gtwi[tid + 256];
    const float* sb = sig + (size_t)b * LOUT;
    int base = t * HOPSZ - PADW;
    #pragma unroll
    for (int r = 0; r < 4; ++r) {
        int j = tid + r * 256;
        int u = base + j;
        if (u < 0) u = -u;
        else if (u >= LOUT) u = 2 * LOUT - 2 - u;  // reflect (no edge repeat)
        Xr[j] = sb[u] * win[j];
        Xi[j] = 0.f;
    }
    fft1024(Xr, Xi, Yr, Yi, twr, twi, tid, +1.f);  // FORWARD; result in X
    __syncthreads();
    const float* mrow = mag + (size_t)f * NFREQ;
    #pragma unroll
    for (int r = 0; r < 2; ++r) {
        int k = tid + r * 256;                     // 0..511
        float sr = Xr[k], si = Xi[k];
        float m = mrow[k];
        float sc = m / (sqrtf(sr * sr + si * si) + 1e-8f);
        float nr = sr * sc, ni = si * sc;
        Yr[k] = nr; Yi[k] = ni;
        if (k >= 1) { Yr[NFFT - k] = nr; Yi[NFFT - k] = -ni; }
    }
    if (tid == 0) {
        float sr = Xr[512], si = Xi[512];
        float m = mrow[512];
        float sc = m / (sqrtf(sr * sr + si * si) + 1e-8f);
        Yr[512] = sr * sc; Yi[512] = si * sc;
    }
    fft1024(Yr, Yi, Xr, Xi, twr, twi, tid, -1.f);  // INVERSE; result in Y
    __syncthreads();
    float* fr = frames + (size_t)f * NFFT;
    #pragma unroll
    for (int r = 0; r < 4; ++r) {
        int j = tid + r * 256;
        fr[j] = Yr[j] * win[j] * (1.0f / NFFT);
    }
}

// ---------------------------------------------------------------------- host
extern "C" void kernel_launch(void* const* d_in, const int* in_sizes, int n_in,
                              void* d_out, int out_size, void* d_ws, size_t ws_size,
                              hipStream_t stream) {
    const float* mel = (const float*)d_in[0];   // (8, 80, 1024)
    const float* ang = (const float*)d_in[1];   // (8, 513, 1024)
    const float* fb  = (const float*)d_in[2];   // (513, 80)
    float* ws = (float*)d_ws;

    float* twr    = ws;                                   // 512
    float* twi    = twr + NHALF;                          // 512
    float* win    = twi + NHALF;                          // 1024
    float* envinv = win + NFFT;                           // LPAD
    float* em     = envinv + LPAD;                        // 8*80*1024
    float* mag    = em + (size_t)BATCH * NMELS * TFRAMES; // 8*1024*513
    float* frames = mag + (size_t)BATCH * TFRAMES * NFREQ;// 8*1024*1024
    float* sig    = frames + (size_t)BATCH * TFRAMES * NFFT; // 8*261888
    float* out    = (float*)d_out;

    k_init_tables<<<4, 256, 0, stream>>>(twr, twi, win);
    k_env<<<(LPAD + 255) / 256, 256, 0, stream>>>(win, envinv);
    k_expmel<<<(BATCH * NMELS * TFRAMES + 255) / 256, 256, 0, stream>>>(mel, em);
    k_mag<<<BATCH * TFRAMES, 128, 0, stream>>>(em, fb, mag);
    k_init_frames<<<BATCH * TFRAMES, 256, 0, stream>>>(mag, ang, twr, twi, win, frames);

    dim3 olag((LOUT + 255) / 256, BATCH);
    for (int it = 0; it < NITER; ++it) {
        k_ola<<<olag, 256, 0, stream>>>(frames, envinv, sig);
        k_glstep<<<BATCH * TFRAMES, 256, 0, stream>>>(sig, mag, twr, twi, win, frames);
    }
    k_ola<<<olag, 256, 0, stream>>>(frames, envinv, out);
}

// Round 4
// 2781.565 us; speedup vs baseline: 1.7378x; 1.7378x over previous
//
#include <hip/hip_runtime.h>
#include <math.h>

#define NFFT   1024
#define NHALF  512
#define HOPSZ  256
#define NMELS  80
#define NFREQ  513
#define BATCH  8
#define TFRAMES 1024
#define PADW   512
#define LPAD   (NFFT + (TFRAMES - 1) * HOPSZ)   // 262912
#define LOUT   (LPAD - 2 * PADW)                // 261888
#define NITER  60
#define PI_D   3.14159265358979323846

// ---------------------------------------------------------------- init tables
// tw1024[j] = e^{-2*pi*i*j/1024} (j<512) ; tw512[j] = e^{-2*pi*i*j/512} (j<256)
__global__ void k_init_tables(float* __restrict__ twr, float* __restrict__ twi,
                              float* __restrict__ t5r, float* __restrict__ t5i,
                              float* __restrict__ win) {
    int j = blockIdx.x * 256 + threadIdx.x;
    if (j < NHALF) {
        double th = -2.0 * PI_D * (double)j / (double)NFFT;
        twr[j] = (float)cos(th);
        twi[j] = (float)sin(th);
    }
    if (j < 256) {
        double th = -2.0 * PI_D * (double)j / 512.0;
        t5r[j] = (float)cos(th);
        t5i[j] = (float)sin(th);
    }
    if (j < NFFT) {
        win[j] = (float)(0.5 - 0.5 * cos(2.0 * PI_D * (double)j / (double)NFFT));
    }
}

__global__ void k_env(const float* __restrict__ win, float* __restrict__ envinv) {
    int i = blockIdx.x * 256 + threadIdx.x;
    if (i >= LPAD) return;
    int thi = i / HOPSZ; if (thi > TFRAMES - 1) thi = TFRAMES - 1;
    int d = i - (NFFT - 1);
    int tlo = (d > 0) ? (d + HOPSZ - 1) / HOPSZ : 0;
    float e = 0.f;
    for (int t = tlo; t <= thi; ++t) { float w = win[i - t * HOPSZ]; e += w * w; }
    envinv[i] = (e > 1e-11f) ? (1.0f / e) : 1.0f;
}

__global__ void k_expmel(const float* __restrict__ mel, float* __restrict__ em) {
    int i = blockIdx.x * 256 + threadIdx.x;
    if (i < BATCH * NMELS * TFRAMES) em[i] = expf(mel[i]);
}

// fbT[m*513+k] = fb[k*80+m]
__global__ void k_fbt(const float* __restrict__ fb, float* __restrict__ fbT) {
    int i = blockIdx.x * 256 + threadIdx.x;
    if (i < NFREQ * NMELS) {
        int k = i / NMELS, m = i - k * NMELS;
        fbT[m * NFREQ + k] = fb[i];
    }
}

// mag[(b*1024+t)*513+k], tiled 16 t per block; coalesced fbT reads reused 16x
__global__ __launch_bounds__(256) void k_mag(const float* __restrict__ em,
                                             const float* __restrict__ fbT,
                                             float* __restrict__ mag) {
    __shared__ float sm[NMELS * 16];               // [m][tt]
    int b = blockIdx.y, t0 = blockIdx.x * 16, tid = threadIdx.x;
    for (int idx = tid; idx < NMELS * 16; idx += 256) {
        int m = idx >> 4, tt = idx & 15;
        sm[idx] = em[(size_t)(b * NMELS + m) * TFRAMES + (t0 + tt)];
    }
    __syncthreads();
    for (int k = tid; k < NFREQ; k += 256) {
        float acc[16];
        #pragma unroll
        for (int tt = 0; tt < 16; ++tt) acc[tt] = 0.f;
        for (int m = 0; m < NMELS; ++m) {
            float w = fbT[m * NFREQ + k];
            #pragma unroll
            for (int tt = 0; tt < 16; ++tt) acc[tt] += w * sm[m * 16 + tt];
        }
        #pragma unroll
        for (int tt = 0; tt < 16; ++tt)
            mag[(size_t)((b << 10) + t0 + tt) * NFREQ + k] = fmaxf(acc[tt], 0.f);
    }
}

// ------------------------------------------------- Stockham radix-2, 512 pts
// 256 threads, 1 butterfly/thread/stage, 9 stages. Input in (xr,xi), OUTPUT in
// (yr,yi) (odd stage count). Table e^{-2pi i j/512}: sgn=+1 FORWARD,
// sgn=-1 INVERSE (unscaled).
__device__ __forceinline__ void fft512(float* xr, float* xi, float* yr, float* yi,
                                       const float* t5r, const float* t5i,
                                       int tid, float sgn) {
    float *ar = xr, *ai = xi, *br = yr, *bi = yi;
    #pragma unroll
    for (int stage = 0; stage < 9; ++stage) {
        int s = 1 << stage;
        __syncthreads();
        int bb = tid;                          // [0,256)
        int hi = bb & ~(s - 1);
        int o1 = bb + hi;
        float x0r = ar[bb],       x0i = ai[bb];
        float x1r = ar[bb + 256], x1i = ai[bb + 256];
        float wr = t5r[hi], wi = sgn * t5i[hi];
        float sr = x0r - x1r, si = x0i - x1i;
        br[o1]     = x0r + x1r;
        bi[o1]     = x0i + x1i;
        br[o1 + s] = sr * wr - si * wi;
        bi[o1 + s] = sr * wi + si * wr;
        float* t0 = ar; ar = br; br = t0;
        float* t1 = ai; ai = bi; bi = t1;
    }
}

// ------------------------------- initial frames: irfft(mag * e^{i2pi ang}) * win
__global__ __launch_bounds__(256) void k_init_frames(
        const float* __restrict__ mag, const float* __restrict__ ang,
        const float* __restrict__ gtwr, const float* __restrict__ gtwi,
        const float* __restrict__ gt5r, const float* __restrict__ gt5i,
        const float* __restrict__ win, float* __restrict__ frames) {
    __shared__ float Xr[NHALF], Xi[NHALF], Yr[NHALF], Yi[NHALF];
    __shared__ float t5r[256], t5i[256];
    int f = blockIdx.x; int b = f >> 10; int t = f & 1023;
    int tid = threadIdx.x;
    t5r[tid] = gt5r[tid]; t5i[tid] = gt5i[tid];
    const float* mrow = mag + (size_t)f * NFREQ;
    const float TWO_PI = 6.283185307179586477f;
    if (tid == 0) {
        // bins 0, 512: imag parts dropped (numpy irfft semantics)
        float a0, s0, c0;
        a0 = ang[((size_t)(b * NFREQ + 0)) * TFRAMES + t] * TWO_PI;
        sincosf(a0, &s0, &c0);
        float p0 = mrow[0] * c0;
        a0 = ang[((size_t)(b * NFREQ + 512)) * TFRAMES + t] * TWO_PI;
        sincosf(a0, &s0, &c0);
        float p512 = mrow[512] * c0;
        Xr[0] = 0.5f * (p0 + p512);
        Xi[0] = 0.5f * (p0 - p512);
        // bin 256: Zinv[256] = conj(X[256])
        a0 = ang[((size_t)(b * NFREQ + 256)) * TFRAMES + t] * TWO_PI;
        sincosf(a0, &s0, &c0);
        Xr[256] = mrow[256] * c0;
        Xi[256] = -(mrow[256] * s0);
    } else {
        int k = tid, j = 512 - k;
        float ak = ang[((size_t)(b * NFREQ + k)) * TFRAMES + t] * TWO_PI;
        float aj = ang[((size_t)(b * NFREQ + j)) * TFRAMES + t] * TWO_PI;
        float sk, ck, sj, cj;
        sincosf(ak, &sk, &ck); sincosf(aj, &sj, &cj);
        float pkr = mrow[k] * ck, pki = mrow[k] * sk;
        float pjr = mrow[j] * cj, pji = mrow[j] * sj;
        float Wr = gtwr[k], Wi = gtwi[k];
        float Cr = 0.5f * (pkr + pjr), Ci = 0.5f * (pki - pji);
        float Dr = 0.5f * (pkr - pjr), Di = 0.5f * (pki + pji);
        float U = Wr * Di - Wi * Dr, V = Wr * Dr + Wi * Di;
        Xr[k] = Cr - U;  Xi[k] = Ci + V;
        Xr[j] = Cr + U;  Xi[j] = -Ci + V;
    }
    fft512(Xr, Xi, Yr, Yi, t5r, t5i, tid, -1.f);   // inverse; result in Y
    __syncthreads();
    float2* fr2 = (float2*)(frames + (size_t)f * NFFT);
    const float2* w2p = (const float2*)win;
    const float SC = 1.0f / 512.0f;
    #pragma unroll
    for (int r = 0; r < 2; ++r) {
        int m = tid + r * 256;
        float2 w2 = w2p[m];
        fr2[m] = make_float2(Yr[m] * w2.x * SC, Yi[m] * w2.y * SC);
    }
}

// ------------------- overlap-add: frames -> signal (len LOUT, env-normalized)
__global__ void k_ola(const float* __restrict__ frames, const float* __restrict__ envinv,
                      float* __restrict__ out) {
    int i = blockIdx.x * 256 + threadIdx.x;
    int b = blockIdx.y;
    if (i >= LOUT) return;
    int ii = i + PADW;
    int thi = ii >> 8; if (thi > TFRAMES - 1) thi = TFRAMES - 1;
    int d = ii - (NFFT - 1);
    int tlo = (d > 0) ? ((d + HOPSZ - 1) >> 8) : 0;
    float acc = 0.f;
    const float* fb_ = frames + (size_t)b * TFRAMES * NFFT;
    for (int t = tlo; t <= thi; ++t) acc += fb_[t * NFFT + (ii - t * HOPSZ)];
    out[(size_t)b * LOUT + i] = acc * envinv[ii];
}

// -------- one GL step per frame: gather+win -> rfft(via c512) -> project -> irfft -> *win
// NOTE: no __syncthreads() inside the divergent unpack section! The unpack reads
// Y and writes X (disjoint arrays, disjoint per-thread indices); fft512's own
// stage-0 barrier provides all needed ordering. A barrier inside the if/else
// made wave 0 issue 2 barriers vs 1 for waves 1-3 -> cascading desync (round 3 bug).
__global__ __launch_bounds__(256) void k_glstep(
        const float* __restrict__ sig, const float* __restrict__ mag,
        const float* __restrict__ gtwr, const float* __restrict__ gtwi,
        const float* __restrict__ gt5r, const float* __restrict__ gt5i,
        const float* __restrict__ win, float* __restrict__ frames) {
    __shared__ float Xr[NHALF], Xi[NHALF], Yr[NHALF], Yi[NHALF];
    __shared__ float t5r[256], t5i[256];
    int f = blockIdx.x; int b = f >> 10; int t = f & 1023;
    int tid = threadIdx.x;
    t5r[tid] = gt5r[tid]; t5i[tid] = gt5i[tid];
    const float* sb = sig + (size_t)b * LOUT;
    const float2* w2p = (const float2*)win;
    int base = t * HOPSZ - PADW;
    // load even/odd packed: z[m] = x[2m]*w[2m] + i*x[2m+1]*w[2m+1]
    #pragma unroll
    for (int r = 0; r < 2; ++r) {
        int m = tid + r * 256;
        int j0 = 2 * m, j1 = 2 * m + 1;
        int u0 = base + j0, u1 = base + j1;
        if (u0 < 0) u0 = -u0; else if (u0 >= LOUT) u0 = 2 * LOUT - 2 - u0;
        if (u1 < 0) u1 = -u1; else if (u1 >= LOUT) u1 = 2 * LOUT - 2 - u1;
        float2 w2 = w2p[m];
        Xr[m] = sb[u0] * w2.x;
        Xi[m] = sb[u1] * w2.y;
    }
    fft512(Xr, Xi, Yr, Yi, t5r, t5i, tid, +1.f);   // forward; Z in Y
    __syncthreads();
    // unpack rfft bins, project to mag, repack inverse input into X
    const float* mrow = mag + (size_t)f * NFREQ;
    if (tid == 0) {
        float Z0r = Yr[0], Z0i = Yi[0];
        float X0 = Z0r + Z0i, X512 = Z0r - Z0i;
        float p0   = mrow[0]   * X0   / (fabsf(X0)   + 1e-8f);
        float p512 = mrow[512] * X512 / (fabsf(X512) + 1e-8f);
        float Zcr = Yr[256], Zci = Yi[256];           // X[256] = conj(Z[256])
        float X256r = Zcr, X256i = -Zci;
        float sc = mrow[256] / (sqrtf(X256r * X256r + X256i * X256i) + 1e-8f);
        Xr[0] = 0.5f * (p0 + p512);
        Xi[0] = 0.5f * (p0 - p512);
        Xr[256] = X256r * sc;
        Xi[256] = -(X256i * sc);                       // Zinv[256] = conj(p256)
    } else {
        int k = tid, j = 512 - k;
        float Zar = Yr[k], Zai = Yi[k], Zbr = Yr[j], Zbi = Yi[j];
        float Ar = 0.5f * (Zar + Zbr), Ai = 0.5f * (Zai - Zbi);
        float Br = 0.5f * (Zar - Zbr), Bi = 0.5f * (Zai + Zbi);
        float Wr = gtwr[k], Wi = gtwi[k];
        float P = Wr * Bi + Wi * Br, Q = Wr * Br - Wi * Bi;
        float Xkr = Ar + P, Xki = Ai - Q;              // X[k]
        float Xjr = Ar - P, Xji = -Ai - Q;             // X[512-k]
        float sck = mrow[k] / (sqrtf(Xkr * Xkr + Xki * Xki) + 1e-8f);
        float scj = mrow[j] / (sqrtf(Xjr * Xjr + Xji * Xji) + 1e-8f);
        float pkr = Xkr * sck, pki = Xki * sck;
        float pjr = Xjr * scj, pji = Xji * scj;
        float Cr = 0.5f * (pkr + pjr), Ci = 0.5f * (pki - pji);
        float Dr = 0.5f * (pkr - pjr), Di = 0.5f * (pki + pji);
        float U = Wr * Di - Wi * Dr, V = Wr * Dr + Wi * Di;
        Xr[k] = Cr - U;  Xi[k] = Ci + V;
        Xr[j] = Cr + U;  Xi[j] = -Ci + V;
    }
    fft512(Xr, Xi, Yr, Yi, t5r, t5i, tid, -1.f);   // inverse; z in Y
    __syncthreads();
    float2* fr2 = (float2*)(frames + (size_t)f * NFFT);
    const float SC = 1.0f / 512.0f;
    #pragma unroll
    for (int r = 0; r < 2; ++r) {
        int m = tid + r * 256;
        float2 w2 = w2p[m];
        fr2[m] = make_float2(Yr[m] * w2.x * SC, Yi[m] * w2.y * SC);
    }
}

// ---------------------------------------------------------------------- host
extern "C" void kernel_launch(void* const* d_in, const int* in_sizes, int n_in,
                              void* d_out, int out_size, void* d_ws, size_t ws_size,
                              hipStream_t stream) {
    const float* mel = (const float*)d_in[0];   // (8, 80, 1024)
    const float* ang = (const float*)d_in[1];   // (8, 513, 1024)
    const float* fb  = (const float*)d_in[2];   // (513, 80)
    float* ws = (float*)d_ws;

    float* twr    = ws;                                   // 512
    float* twi    = twr + NHALF;                          // 512
    float* t5r    = twi + NHALF;                          // 256
    float* t5i    = t5r + 256;                            // 256
    float* win    = t5i + 256;                            // 1024
    float* fbT    = win + NFFT;                           // 80*513
    float* envinv = fbT + NMELS * NFREQ;                  // LPAD
    float* em     = envinv + LPAD;                        // 8*80*1024
    float* mag    = em + (size_t)BATCH * NMELS * TFRAMES; // 8*1024*513
    float* frames = mag + (size_t)BATCH * TFRAMES * NFREQ;// 8*1024*1024
    float* sig    = frames + (size_t)BATCH * TFRAMES * NFFT; // 8*261888
    float* out    = (float*)d_out;

    k_init_tables<<<4, 256, 0, stream>>>(twr, twi, t5r, t5i, win);
    k_env<<<(LPAD + 255) / 256, 256, 0, stream>>>(win, envinv);
    k_expmel<<<(BATCH * NMELS * TFRAMES + 255) / 256, 256, 0, stream>>>(mel, em);
    k_fbt<<<(NFREQ * NMELS + 255) / 256, 256, 0, stream>>>(fb, fbT);
    {
        dim3 g(TFRAMES / 16, BATCH);
        k_mag<<<g, 256, 0, stream>>>(em, fbT, mag);
    }
    k_init_frames<<<BATCH * TFRAMES, 256, 0, stream>>>(mag, ang, twr, twi, t5r, t5i, win, frames);

    dim3 olag((LOUT + 255) / 256, BATCH);
    for (int it = 0; it < NITER; ++it) {
        k_ola<<<olag, 256, 0, stream>>>(frames, envinv, sig);
        k_glstep<<<BATCH * TFRAMES, 256, 0, stream>>>(sig, mag, twr, twi, t5r, t5i, win, frames);
    }
    k_ola<<<olag, 256, 0, stream>>>(frames, envinv, out);
}